// Round 4
// baseline (1645.727 us; speedup 1.0000x reference)
//
#include <hip/hip_runtime.h>

// GrCNN: B=32, L=128, D=256, 127 sequential levels.
// Round 4: 32 blocks (one per sentence), 4 waves, NO inter-block sync.
// W column-slice resident in VGPRs per wave (4 central 16-col MFMA B-tiles
// + gate tile + one-hot extraction tiles). State ping-pongs in LDS (2x64KB).
// lv/rv for the epilogue come from one-hot MFMA "extraction" (register
// transpose in hardware) instead of scalar LDS reads. One syncthreads/level.

#define B_ 32
#define L_ 128
#define D_ 256
#define LOG2E 1.4426950408889634f

typedef _Float16 half8 __attribute__((ext_vector_type(8)));
typedef float f32x4 __attribute__((ext_vector_type(4)));

// ---- WT[272][512] fp16: col j -> 512 k (k<256: Wl/Gl row k, else Wr/Gr) ----
__global__ void prep_wt(const float* __restrict__ Wl, const float* __restrict__ Wr,
                        const float* __restrict__ Gl, const float* __restrict__ Gr,
                        _Float16* __restrict__ WT) {
    int j = blockIdx.x;
    for (int k = threadIdx.x; k < 512; k += 256) {
        float v = 0.f;
        if (j < 256) v = (k < 256) ? Wl[k * 256 + j] : Wr[(k - 256) * 256 + j];
        else { int jj = j - 256; if (jj < 3) v = (k < 256) ? Gl[k * 3 + jj] : Gr[(k - 256) * 3 + jj]; }
        WT[(size_t)j * 512 + k] = (_Float16)v;
    }
}

#define SWZ(o) ((o) ^ ((((o) >> 9) & 7) << 4))
#define MFMA16 __builtin_amdgcn_mfma_f32_16x16x32_f16

__global__ __launch_bounds__(256, 1) void grcnn_main(
    const float* __restrict__ x, const _Float16* __restrict__ WT,
    const float* __restrict__ Wb, const float* __restrict__ Gb,
    float* __restrict__ out)
{
    __shared__ alignas(16) char lds[131072];   // two 64KB state buffers
    char* buf0 = lds;
    char* buf1 = lds + 65536;

    const int tid = threadIdx.x, b = blockIdx.x;
    const int w = tid >> 6, l = tid & 63, lr = l & 15, q = l >> 4;
    const int cw = w * 64;                      // wave's 64-col slab

    // ---- W fragments -> VGPRs (resident for whole kernel) ----
    half8 wf0[16], wf1[16], wf2[16], wf3[16], wfg[16];
    #pragma unroll
    for (int s = 0; s < 16; ++s) {
        const _Float16* p = WT + s * 32 + q * 8;
        wf0[s] = *(const half8*)(p + (size_t)(cw +      lr) * 512);
        wf1[s] = *(const half8*)(p + (size_t)(cw + 16 + lr) * 512);
        wf2[s] = *(const half8*)(p + (size_t)(cw + 32 + lr) * 512);
        wf3[s] = *(const half8*)(p + (size_t)(cw + 48 + lr) * 512);
        wfg[s] = *(const half8*)(p + (size_t)(256 +     lr) * 512);
    }
    // one-hot extraction B-frags: tile NT extracts S[row][cw+NT*16+lr].
    // nonzero lane: q == (NT&1)*2 + (lr>>3), element lr&7.
    half8 oh0 = {}, oh1 = {}, oh2 = {}, oh3 = {};
    #pragma unroll
    for (int j = 0; j < 8; ++j) {
        if (j == (lr & 7)) {
            _Float16 one = (_Float16)1.0f;
            if (q == (0 + (lr >> 3))) oh0[j] = one;
            if (q == (2 + (lr >> 3))) oh1[j] = one;
            if (q == (0 + (lr >> 3))) oh2[j] = one;
            if (q == (2 + (lr >> 3))) oh3[j] = one;
        }
    }
    const float wb0 = Wb[cw + lr], wb1 = Wb[cw + 16 + lr];
    const float wb2 = Wb[cw + 32 + lr], wb3 = Wb[cw + 48 + lr];
    const float gb0 = Gb[0], gb1 = Gb[1], gb2 = Gb[2];

    // ---- stage x -> fp16 buf0 (swizzled) ----
    for (int ch = tid; ch < 128 * 64; ch += 256) {
        int row = ch >> 6, c4 = ch & 63;
        const float* xp = x + ((size_t)b * L_ + row) * D_ + c4 * 4;
        float v0 = xp[0], v1 = xp[1], v2 = xp[2], v3 = xp[3];
        unsigned lo = (unsigned)__builtin_bit_cast(unsigned short, (_Float16)v0)
                    | ((unsigned)__builtin_bit_cast(unsigned short, (_Float16)v1) << 16);
        unsigned hi = (unsigned)__builtin_bit_cast(unsigned short, (_Float16)v2)
                    | ((unsigned)__builtin_bit_cast(unsigned short, (_Float16)v3) << 16);
        int off = row * 512 + c4 * 8;
        unsigned* d = (unsigned*)(buf0 + SWZ(off));
        d[0] = lo; d[1] = hi;
    }
    // ---- level-0 output: col max over all 128 rows (from fp32 x) ----
    {
        float m0 = -3.4e38f;
        for (int row = 0; row < 128; ++row)
            m0 = fmaxf(m0, x[((size_t)b * L_ + row) * D_ + tid]);
        out[(size_t)b * L_ * D_ + tid] = m0;
    }
    __syncthreads();

    // ---- 127 sequential levels ----
    for (int t = 0; t < 127; ++t) {
        const int n = 127 - t;
        char* src = (t & 1) ? buf1 : buf0;
        char* dst = (t & 1) ? buf0 : buf1;
        const int ntile = (n + 15) >> 4;
        float cm0 = -3.4e38f, cm1 = -3.4e38f, cm2 = -3.4e38f, cm3 = -3.4e38f;

        for (int tau = 0; tau < ntile; ++tau) {
            const int rowb = tau * 16;
            f32x4 a0 = {}, a1 = {}, a2 = {}, a3 = {}, ag = {};
            #pragma unroll
            for (int s = 0; s < 16; ++s) {
                int ao = (rowb + lr) * 512 + s * 64 + q * 16;
                half8 av = *(const half8*)(src + SWZ(ao));
                a0 = MFMA16(av, wf0[s], a0, 0, 0, 0);
                a1 = MFMA16(av, wf1[s], a1, 0, 0, 0);
                a2 = MFMA16(av, wf2[s], a2, 0, 0, 0);
                a3 = MFMA16(av, wf3[s], a3, 0, 0, 0);
                ag = MFMA16(av, wfg[s], ag, 0, 0, 0);
            }
            // lv extraction: re-read the two k-steps covering cols [cw, cw+64)
            int axo = (rowb + lr) * 512 + (w * 2) * 64 + q * 16;
            half8 ax0 = *(const half8*)(src + SWZ(axo));
            half8 ax1 = *(const half8*)(src + SWZ(axo + 64));
            f32x4 z = {};
            f32x4 e0 = MFMA16(ax0, oh0, z, 0, 0, 0);
            f32x4 e1 = MFMA16(ax0, oh1, z, 0, 0, 0);
            f32x4 e2 = MFMA16(ax1, oh2, z, 0, 0, 0);
            f32x4 e3 = MFMA16(ax1, oh3, z, 0, 0, 0);

            // boundary lv (row rowb+16) for q==3,r==3 cells
            int brow = (rowb + 16 <= 127) ? rowb + 16 : 127;
            float bl0 = (float)*(const _Float16*)(src + SWZ(brow * 512 + (cw +      lr) * 2));
            float bl1 = (float)*(const _Float16*)(src + SWZ(brow * 512 + (cw + 16 + lr) * 2));
            float bl2 = (float)*(const _Float16*)(src + SWZ(brow * 512 + (cw + 32 + lr) * 2));
            float bl3 = (float)*(const _Float16*)(src + SWZ(brow * 512 + (cw + 48 + lr) * 2));
            // next-q-group row0 lv (for r==3, q<3)
            int nl = (l + 16) & 63;
            float s0 = __shfl(e0[0], nl, 64);
            float s1 = __shfl(e1[0], nl, 64);
            float s2 = __shfl(e2[0], nl, 64);
            float s3 = __shfl(e3[0], nl, 64);

            #pragma unroll
            for (int r = 0; r < 4; ++r) {
                const int row = rowb + q * 4 + r;
                float p0 = __shfl(ag[r], (l & 48) + 0, 64) + gb0;
                float p1 = __shfl(ag[r], (l & 48) + 1, 64) + gb1;
                float p2 = __shfl(ag[r], (l & 48) + 2, 64) + gb2;
                if (row < n) {
                    float mg = fmaxf(fmaxf(p0, p1), p2);
                    float ee0 = exp2f((p0 - mg) * LOG2E);
                    float ee1 = exp2f((p1 - mg) * LOG2E);
                    float ee2 = exp2f((p2 - mg) * LOG2E);
                    float inv = __builtin_amdgcn_rcpf(ee0 + ee1 + ee2);
                    float g0f = ee0 * inv, g1f = ee1 * inv, g2f = ee2 * inv;

                    #define EPI(NT, ACCV, EV, WBV, BLV, SHV, CMV) {                              \
                        float pre = ACCV[r] + WBV;                                               \
                        float exx = exp2f(pre * (2.f * LOG2E));                                  \
                        float ce = 1.f - 2.f * __builtin_amdgcn_rcpf(exx + 1.f);                 \
                        float lv = EV[r];                                                        \
                        float rv = (r < 3) ? EV[(r < 3) ? r + 1 : 0] : (q < 3 ? SHV : BLV);      \
                        float nx = g0f * lv + g1f * ce + g2f * rv;                               \
                        CMV = fmaxf(CMV, nx);                                                    \
                        int pdi = __builtin_amdgcn_update_dpp(                                   \
                            0, __builtin_bit_cast(int, nx), 0xB1, 0xF, 0xF, true);               \
                        float pnx = __builtin_bit_cast(float, pdi);                              \
                        unsigned pk = (unsigned)__builtin_bit_cast(unsigned short, (_Float16)nx) \
                            | ((unsigned)__builtin_bit_cast(unsigned short, (_Float16)pnx) << 16);\
                        if (!(lr & 1)) {                                                         \
                            int wo = row * 512 + (cw + NT * 16 + lr) * 2;                        \
                            *(unsigned*)(dst + SWZ(wo)) = pk;                                    \
                        }                                                                        \
                    }
                    EPI(0, a0, e0, wb0, bl0, s0, cm0)
                    EPI(1, a1, e1, wb1, bl1, s1, cm1)
                    EPI(2, a2, e2, wb2, bl2, s2, cm2)
                    EPI(3, a3, e3, wb3, bl3, s3, cm3)
                    #undef EPI
                }
            }
        }

        // col-max across the 4 q-groups (cols are per-lane lr within each tile)
        cm0 = fmaxf(cm0, __shfl_xor(cm0, 16, 64)); cm0 = fmaxf(cm0, __shfl_xor(cm0, 32, 64));
        cm1 = fmaxf(cm1, __shfl_xor(cm1, 16, 64)); cm1 = fmaxf(cm1, __shfl_xor(cm1, 32, 64));
        cm2 = fmaxf(cm2, __shfl_xor(cm2, 16, 64)); cm2 = fmaxf(cm2, __shfl_xor(cm2, 32, 64));
        cm3 = fmaxf(cm3, __shfl_xor(cm3, 16, 64)); cm3 = fmaxf(cm3, __shfl_xor(cm3, 32, 64));
        if (l < 16) {
            float* o = out + ((size_t)b * L_ + (t + 1)) * D_ + cw;
            o[l] = cm0; o[16 + l] = cm1; o[32 + l] = cm2; o[48 + l] = cm3;
        }
        __syncthreads();   // dst complete before it becomes src
    }
}

extern "C" void kernel_launch(void* const* d_in, const int* in_sizes, int n_in,
                              void* d_out, int out_size, void* d_ws, size_t ws_size,
                              hipStream_t stream) {
    const float* x  = (const float*)d_in[0];
    const float* Wl = (const float*)d_in[1];
    const float* Wr = (const float*)d_in[2];
    const float* Wb = (const float*)d_in[3];
    const float* Gl = (const float*)d_in[4];
    const float* Gr = (const float*)d_in[5];
    const float* Gb = (const float*)d_in[6];
    float* out = (float*)d_out;

    _Float16* WT = (_Float16*)d_ws;   // 272*512*2 = 278528 bytes

    prep_wt<<<272, 256, 0, stream>>>(Wl, Wr, Gl, Gr, WT);
    grcnn_main<<<B_, 256, 0, stream>>>(x, WT, Wb, Gb, out);
}

// Round 6
// 690.266 us; speedup vs baseline: 2.3842x; 2.3842x over previous
//
#include <hip/hip_runtime.h>

// GrCNN: B=32, L=128, D=256, 127 sequential levels.
// Round 6: row-slab decomposition (fixed). 256 blocks = (sentence b, slab h:
// rows 16h..16h+15). 8 waves/block, wave w owns cols [32w,32w+32); W resident
// in VGPRs. State: 17 LDS rows, ping-pong. FIX vs round 5: the MFMA A-read
// spans rows lr..lr+1 (implicit [left|right] concat), so the boundary row 16
// import must land BEFORE the MFMA, behind a barrier. One-hot extraction
// (rows 0..15 only) overlaps the import. Both LDS buffers staged at init so
// no uninitialized LDS is ever read (NaN-proof).

#define B_ 32
#define L_ 128
#define D_ 256
#define NTHR 512
#define LOG2E 1.4426950408889634f

typedef _Float16 half8 __attribute__((ext_vector_type(8)));
typedef float f32x4 __attribute__((ext_vector_type(4)));

#define SWZ(o) ((o) ^ ((((o) >> 9) & 7) << 4))
#define MFMA16 __builtin_amdgcn_mfma_f32_16x16x32_f16

// ---- WT[272][512] fp16: col j -> 512 k (k<256: Wl/Gl row k, else Wr/Gr) ----
__global__ void prep_wt(const float* __restrict__ Wl, const float* __restrict__ Wr,
                        const float* __restrict__ Gl, const float* __restrict__ Gr,
                        _Float16* __restrict__ WT) {
    int j = blockIdx.x;
    for (int k = threadIdx.x; k < 512; k += 256) {
        float v = 0.f;
        if (j < 256) v = (k < 256) ? Wl[k * 256 + j] : Wr[(k - 256) * 256 + j];
        else { int jj = j - 256; if (jj < 3) v = (k < 256) ? Gl[k * 3 + jj] : Gr[(k - 256) * 3 + jj]; }
        WT[(size_t)j * 512 + k] = (_Float16)v;
    }
}

// ---- init: zero flags/acks, zero enc, level-0 col max ----
__global__ void init_misc(const float* __restrict__ x, float* __restrict__ out,
                          unsigned* __restrict__ enc, int* __restrict__ flags) {
    int b = blockIdx.x, c = threadIdx.x;
    if (b == 0) for (int i = c; i < 2 * 256 * 16; i += 256) flags[i] = 0;
    for (int k = 0; k < L_; ++k) enc[((size_t)b * L_ + k) * D_ + c] = 0u;
    float m = -3.4e38f;
    for (int row = 0; row < L_; ++row)
        m = fmaxf(m, x[((size_t)b * L_ + row) * D_ + c]);
    out[(size_t)b * L_ * D_ + c] = m;
}

// ---- decode: enc -> out for levels 1..127 ----
__global__ void decode_out(const unsigned* __restrict__ enc, float* __restrict__ out) {
    for (size_t i = (size_t)blockIdx.x * 256 + threadIdx.x; i < (size_t)32 * 128 * 256;
         i += (size_t)gridDim.x * 256) {
        unsigned k = (unsigned)((i >> 8) & 127);
        if (k == 0) continue;
        unsigned u = enc[i];
        unsigned bitsv = (u & 0x80000000u) ? (u & 0x7FFFFFFFu) : ~u;
        out[i] = __builtin_bit_cast(float, bitsv);
    }
}

__global__ __launch_bounds__(NTHR, 2) void grcnn_main(
    const float* __restrict__ x, const _Float16* __restrict__ WT,
    const float* __restrict__ Wb, const float* __restrict__ Gb,
    unsigned* __restrict__ enc, unsigned long long* __restrict__ brow,
    int* __restrict__ flags)
{
    __shared__ alignas(16) char lds[2 * 8704];
    char* bufA = lds;
    char* bufB = lds + 8704;

    const int tid = threadIdx.x;
    const int b = blockIdx.x & 31, h = blockIdx.x >> 5;
    const int w = tid >> 6, l = tid & 63, lr = l & 15, q = l >> 4;
    const int cw = w * 32;

    // ---- W fragments resident in VGPRs ----
    half8 wf0[16], wf1[16], wfg[16];
    #pragma unroll
    for (int s = 0; s < 16; ++s) {
        const _Float16* p = WT + s * 32 + q * 8;
        wf0[s] = *(const half8*)(p + (size_t)(cw + lr) * 512);
        wf1[s] = *(const half8*)(p + (size_t)(cw + 16 + lr) * 512);
        wfg[s] = *(const half8*)(p + (size_t)(256 + lr) * 512);
    }
    // one-hot extraction frags: tile NT extracts S[row][cw+NT*16+lr]
    half8 oh0 = {}, oh1 = {};
    {
        _Float16 one = (_Float16)1.0f;
        #pragma unroll
        for (int j = 0; j < 8; ++j) if (j == (lr & 7)) {
            if (q == (lr >> 3))     oh0[j] = one;   // k_local = lr
            if (q == 2 + (lr >> 3)) oh1[j] = one;   // k_local = 16 + lr
        }
    }
    const float wb0 = Wb[cw + lr], wb1 = Wb[cw + 16 + lr];
    const float gb0 = Gb[0], gb1 = Gb[1], gb2 = Gb[2];

    int* flagA = flags;            // [256] stride-16 dwords
    int* ackA  = flags + 256 * 16;

    // ---- stage rows 16h..16h+16 (17 rows, clamped) into BOTH buffers ----
    for (int ch = tid; ch < 17 * 32; ch += NTHR) {
        int row = ch >> 5, kc = ch & 31;
        int grow = 16 * h + row; if (grow > 127) grow = 127;
        const float* xp = x + ((size_t)b * L_ + grow) * D_ + kc * 8;
        half8 v;
        #pragma unroll
        for (int j = 0; j < 8; ++j) v[j] = (_Float16)xp[j];
        int off = SWZ(row * 512 + kc * 16);
        *(half8*)(bufA + off) = v;
        *(half8*)(bufB + off) = v;
    }
    __syncthreads();

    char* src = bufA;
    char* dst = bufB;

    for (int t = 0; t < 127; ++t) {
        const int n = 127 - t;
        const int m = n - 16 * h;
        if (m <= 0) break;
        const int mm = (m > 16) ? 16 : m;
        const bool doImp = (t >= 1) && (m >= 16);
        const bool doExp = (h >= 1) && (126 - t >= 16 * h);

        // ---- wave 0: import boundary row (level-t state row 16h+16) ----
        if (w == 0 && doImp) {
            int* fp = flagA + (b * 8 + h + 1) * 16;
            while (__hip_atomic_load(fp, __ATOMIC_RELAXED, __HIP_MEMORY_SCOPE_AGENT) < t)
                __builtin_amdgcn_s_sleep(1);
            const unsigned long long* bp =
                brow + (((size_t)(t & 1) * 32 + b) * 8 + (h + 1)) * 64 + l;
            unsigned long long impv =
                __hip_atomic_load(bp, __ATOMIC_RELAXED, __HIP_MEMORY_SCOPE_AGENT);
            asm volatile("s_waitcnt vmcnt(0)" ::: "memory");
            *(unsigned long long*)(src + 8192 + l * 8) = impv;   // row 16 (identity swz)
            if (l == 0)
                __hip_atomic_store(ackA + (b * 8 + h) * 16, t,
                                   __ATOMIC_RELAXED, __HIP_MEMORY_SCOPE_AGENT);
        }

        // ---- all waves: one-hot lv extraction (rows 0..15 only, overlaps import) ----
        int axo = lr * 512 + w * 64 + q * 16;
        half8 ax = *(const half8*)(src + SWZ(axo));
        f32x4 z = {};
        f32x4 e0 = MFMA16(ax, oh0, z, 0, 0, 0);
        f32x4 e1 = MFMA16(ax, oh1, z, 0, 0, 0);

        __syncthreads();   // #1: boundary row 16 in place before main MFMA

        // ---- MFMA: A spans rows lr..lr+1 (incl row 16); K=512 ----
        f32x4 a0 = {}, a1 = {}, ag = {};
        #pragma unroll
        for (int s = 0; s < 16; ++s) {
            int ao = lr * 512 + s * 64 + q * 16;
            half8 av = *(const half8*)(src + SWZ(ao));
            a0 = MFMA16(av, wf0[s], a0, 0, 0, 0);
            a1 = MFMA16(av, wf1[s], a1, 0, 0, 0);
            ag = MFMA16(av, wfg[s], ag, 0, 0, 0);
        }

        // ---- epilogue ----
        int nl = (l + 16) & 63;
        float s0 = __shfl(e0[0], nl, 64);
        float s1 = __shfl(e1[0], nl, 64);
        float bl0 = (float)*(const _Float16*)(src + 8192 + (cw + lr) * 2);
        float bl1 = (float)*(const _Float16*)(src + 8192 + (cw + 16 + lr) * 2);

        float cm0 = -3.4e38f, cm1 = -3.4e38f;
        #pragma unroll
        for (int r = 0; r < 4; ++r) {
            const int row = q * 4 + r;
            float p0 = __shfl(ag[r], (l & 48) + 0, 64) + gb0;
            float p1 = __shfl(ag[r], (l & 48) + 1, 64) + gb1;
            float p2 = __shfl(ag[r], (l & 48) + 2, 64) + gb2;
            if (row < mm) {
                float mg = fmaxf(fmaxf(p0, p1), p2);
                float ee0 = exp2f((p0 - mg) * LOG2E);
                float ee1 = exp2f((p1 - mg) * LOG2E);
                float ee2 = exp2f((p2 - mg) * LOG2E);
                float inv = __builtin_amdgcn_rcpf(ee0 + ee1 + ee2);
                float g0f = ee0 * inv, g1f = ee1 * inv, g2f = ee2 * inv;

                #define EPI(NT, ACC, EV, WBV, BLV, SHV, CMV) {                               \
                    float pre = ACC[r] + WBV;                                                \
                    float exx = exp2f(pre * (2.f * LOG2E));                                  \
                    float ce = 1.f - 2.f * __builtin_amdgcn_rcpf(exx + 1.f);                 \
                    float lv = EV[r];                                                        \
                    float rv = (r < 3) ? EV[(r < 3) ? r + 1 : 0] : (q < 3 ? SHV : BLV);      \
                    float nx = g0f * lv + g1f * ce + g2f * rv;                               \
                    CMV = fmaxf(CMV, nx);                                                    \
                    int pdi = __builtin_amdgcn_update_dpp(                                   \
                        0, __builtin_bit_cast(int, nx), 0xB1, 0xF, 0xF, true);               \
                    float pnx = __builtin_bit_cast(float, pdi);                              \
                    unsigned pk = (unsigned)__builtin_bit_cast(unsigned short, (_Float16)nx) \
                        | ((unsigned)__builtin_bit_cast(unsigned short, (_Float16)pnx) << 16);\
                    if (!(lr & 1)) {                                                         \
                        int wo = row * 512 + (cw + NT * 16 + lr) * 2;                        \
                        *(unsigned*)(dst + SWZ(wo)) = pk;                                    \
                    }                                                                        \
                }
                EPI(0, a0, e0, wb0, bl0, s0, cm0)
                EPI(1, a1, e1, wb1, bl1, s1, cm1)
                #undef EPI
            }
        }

        // col-max across q-groups -> encoded atomic umax into enc[b][t+1][col]
        cm0 = fmaxf(cm0, __shfl_xor(cm0, 16, 64)); cm0 = fmaxf(cm0, __shfl_xor(cm0, 32, 64));
        cm1 = fmaxf(cm1, __shfl_xor(cm1, 16, 64)); cm1 = fmaxf(cm1, __shfl_xor(cm1, 32, 64));
        if (l < 16) {
            int bi0 = __builtin_bit_cast(int, cm0);
            int bi1 = __builtin_bit_cast(int, cm1);
            unsigned u0 = (bi0 < 0) ? ~(unsigned)bi0 : ((unsigned)bi0 | 0x80000000u);
            unsigned u1 = (bi1 < 0) ? ~(unsigned)bi1 : ((unsigned)bi1 | 0x80000000u);
            unsigned* ep = enc + ((size_t)b * L_ + (t + 1)) * D_ + cw;
            __hip_atomic_fetch_max(ep + l, u0, __ATOMIC_RELAXED, __HIP_MEMORY_SCOPE_AGENT);
            __hip_atomic_fetch_max(ep + 16 + l, u1, __ATOMIC_RELAXED, __HIP_MEMORY_SCOPE_AGENT);
        }
        __syncthreads();   // #2: dst rows complete

        // ---- wave 1: export dst row 0 (slot depth-2, ack-protected) ----
        if (w == 1 && doExp) {
            if (t >= 2 && (128 - t) >= 16 * h) {
                int* ap = ackA + (b * 8 + (h - 1)) * 16;
                while (__hip_atomic_load(ap, __ATOMIC_RELAXED, __HIP_MEMORY_SCOPE_AGENT) < t - 1)
                    __builtin_amdgcn_s_sleep(1);
            }
            unsigned long long v = *(const unsigned long long*)(dst + l * 8);
            unsigned long long* bp =
                brow + (((size_t)((t + 1) & 1) * 32 + b) * 8 + h) * 64 + l;
            __hip_atomic_store(bp, v, __ATOMIC_RELAXED, __HIP_MEMORY_SCOPE_AGENT);
            asm volatile("s_waitcnt vmcnt(0)" ::: "memory");
            if (l == 0)
                __hip_atomic_store(flagA + (b * 8 + h) * 16, t + 1,
                                   __ATOMIC_RELAXED, __HIP_MEMORY_SCOPE_AGENT);
        }
        { char* tmp = src; src = dst; dst = tmp; }
    }
}

extern "C" void kernel_launch(void* const* d_in, const int* in_sizes, int n_in,
                              void* d_out, int out_size, void* d_ws, size_t ws_size,
                              hipStream_t stream) {
    const float* x  = (const float*)d_in[0];
    const float* Wl = (const float*)d_in[1];
    const float* Wr = (const float*)d_in[2];
    const float* Wb = (const float*)d_in[3];
    const float* Gl = (const float*)d_in[4];
    const float* Gr = (const float*)d_in[5];
    const float* Gb = (const float*)d_in[6];
    float* out = (float*)d_out;
    char* ws = (char*)d_ws;

    _Float16* WT = (_Float16*)ws;                                  // 278,528 B
    unsigned long long* brow = (unsigned long long*)(ws + 278528); // 262,144 B
    int* flags = (int*)(ws + 278528 + 262144);                     // 32,768 B
    unsigned* enc = (unsigned*)(ws + 278528 + 262144 + 32768);     // 4 MB

    prep_wt<<<272, 256, 0, stream>>>(Wl, Wr, Gl, Gr, WT);
    init_misc<<<B_, 256, 0, stream>>>(x, out, enc, flags);

    void* args[] = { (void*)&x, (void*)&WT, (void*)&Wb, (void*)&Gb,
                     (void*)&enc, (void*)&brow, (void*)&flags };
    hipLaunchCooperativeKernel((const void*)grcnn_main, dim3(B_ * 8), dim3(NTHR),
                               args, 0, stream);

    decode_out<<<1024, 256, 0, stream>>>(enc, out);
}